// Round 14
// baseline (216.122 us; speedup 1.0000x reference)
//
#include <hip/hip_runtime.h>
#include <hip/hip_fp16.h>

#define Q_TOT 1024
#define T_TOT 256
#define NPTS  100
#define KD    300
#define EPSV  1e-6f

#define KSTEPS 10            // 10 * 32 = 320 >= 300 (zero-padded K)
#define MT     14            // 7 M-tiles fwd (rows 0..111) + 7 bwd

typedef _Float16 f16;
typedef _Float16 f16x8 __attribute__((ext_vector_type(8)));
typedef float    f32x4 __attribute__((ext_vector_type(4)));
#define MFMA16 __builtin_amdgcn_mfma_f32_16x16x32_f16

// ws layout (floats):
//   [0,1024)        p2[q] = sum(pred_q^2)
//   [1024,1280)     v2[t] = sum(tgt_t^2)
//   [1280,+327680)  pfrag: B-fragments, f16x8 idx = ((nt*10+ks)*2+s)*64+lane
//   [WS_AF, ...)    afrag: per-target A-fragments, f16x8 idx =
//                   t*17920 + ((mt*10+ks)*2+s)*64+lane   (73.4 MB)
#define WS_PF 1280
#define WS_AF (WS_PF + 81920*4)
#define AFRAG_PER_T (MT*KSTEPS*2*64)   // 17920 f16x8 per target

// ---------------------------------------------------------------------------
// Fused prep: one block per target (a) A-fragments, (b) pfrag slice,
// (c) p2/v2 scalars with the exact sequential fmaf order (bit-identical).
// ---------------------------------------------------------------------------
__global__ __launch_bounds__(512) void prep_all(const float* __restrict__ preds,
                                                const float* __restrict__ tgt,
                                                float* __restrict__ ws)
{
    __shared__ float extF[600], extR[600];
    const int t   = blockIdx.x;
    const int tid = threadIdx.x;
    const float* tg = tgt + t*KD;

    // (b) pfrag slice: 81920 total / 256 blocks = 320 per block
    if (tid < 320) {
        int idx  = t*320 + tid;
        int lane = idx & 63;
        int r    = idx >> 6;
        int s    = r & 1;  r >>= 1;
        int ks   = r % KSTEPS;
        int nt   = r / KSTEPS;
        int q    = nt*16 + (lane & 15);
        int kb   = ks*32 + (lane >> 4)*8;
        f16x8 v;
        #pragma unroll
        for (int j = 0; j < 8; ++j) {
            int k = kb + j;
            float x = (k < KD) ? preds[q*KD + k] : 0.f;
            f16 h = (f16)x;
            v[j] = s ? (f16)(x - (float)h) : h;
        }
        ((f16x8*)(ws + WS_PF))[idx] = v;
    }

    // (c) scalars -- same sequential order as the original prep_scalars
    if (tid >= 448 && tid < 452) {
        int q = t*4 + (tid - 448);
        const float* p = preds + q*KD;
        float s = 0.f;
        for (int k = 0; k < KD; ++k) s = fmaf(p[k], p[k], s);
        ws[q] = s;
    }
    if (tid == 452) {
        float s = 0.f;
        for (int k = 0; k < KD; ++k) s = fmaf(tg[k], tg[k], s);
        ws[1024 + t] = s;
    }

    // ext staging for afrag
    for (int x = tid; x < 600; x += 512) {
        int m = (x >= 300) ? x-300 : x;
        extF[x] = tg[m];
        int jj = m / 3, c3 = m - 3*jj;
        extR[x] = tg[(NPTS-1-jj)*3 + c3];
    }
    __syncthreads();

    // (a) A-fragments in exact MFMA operand order
    f16x8* outp = (f16x8*)(ws + WS_AF) + t*AFRAG_PER_T;
    for (int j = tid; j < AFRAG_PER_T; j += 512) {
        int lane = j & 63;
        int r    = j >> 6;
        int s    = r & 1;  r >>= 1;
        int ks   = r % KSTEPS;
        int mt   = r / KSTEPS;
        int col  = lane & 15;
        int rg   = lane >> 4;
        int mtp  = (mt < 7) ? mt : mt-7;
        int a    = mtp*16 + col;
        const float* ext = (mt < 7) ? extF : extR;
        f16x8 v;
        #pragma unroll
        for (int jj = 0; jj < 8; ++jj) {
            int k = ks*32 + rg*8 + jj;
            float x = (a < 100 && k < KD) ? ext[300 - 3*a + k] : 0.f;
            f16 h = (f16)x;
            v[jj] = s ? (f16)(x - (float)h) : h;
        }
        outp[j] = v;
    }
}

// ---------------------------------------------------------------------------
// One sweep: NMT M-tiles x 8 N-tiles, K=320.  acc[NMT][8] in AGPRs; the ks
// loop is NOT unrolled -- R12/R13 let the unroller hoist up to 80 dwordx4
// dests into the 128-arch-VGPR budget -> 47 MB/launch scratch spill.  Each
// iteration already carries 24 MFMAs + 20 loads of ILP.
// ---------------------------------------------------------------------------
template<int MTB, int NMT>
__device__ __forceinline__ void sweep(const f16x8* __restrict__ afrag,
                                      const f16x8* __restrict__ pfrag,
                                      int ntb, int lane, int col, int rg,
                                      float v2t, const float (&p2v)[8],
                                      float (&minD)[8], int (&minI)[8],
                                      float (*sopen)[1024])
{
    f32x4 acc[NMT][8];
    #pragma unroll
    for (int h = 0; h < NMT; ++h)
        #pragma unroll
        for (int nt = 0; nt < 8; ++nt) acc[h][nt] = (f32x4){0.f,0.f,0.f,0.f};

    #pragma clang loop unroll(disable)
    for (int ks = 0; ks < KSTEPS; ++ks) {
        f16x8 ah[NMT], alo[NMT];
        #pragma unroll
        for (int h = 0; h < NMT; ++h) {
            const int i = ((MTB+h)*KSTEPS + ks)*128 + lane;
            ah[h]  = afrag[i];
            alo[h] = afrag[i + 64];
        }
        #pragma unroll
        for (int nt = 0; nt < 8; ++nt) {
            const int fi = ((ntb+nt)*KSTEPS + ks)*128 + lane;
            f16x8 bh = pfrag[fi];
            f16x8 bl = pfrag[fi + 64];
            #pragma unroll
            for (int h = 0; h < NMT; ++h) {
                acc[h][nt] = MFMA16(ah[h],  bh, acc[h][nt], 0,0,0);
                acc[h][nt] = MFMA16(ah[h],  bl, acc[h][nt], 0,0,0);
                acc[h][nt] = MFMA16(alo[h], bh, acc[h][nt], 0,0,0);
            }
        }
    }

    #pragma unroll
    for (int h = 0; h < NMT; ++h) {
        const int mt   = MTB + h;
        const int mtp  = (mt < 7) ? mt : mt-7;
        const int voff = (mt < 7) ? 0 : 100;
        const int ab   = mtp*16 + rg*4;
        #pragma unroll
        for (int nt = 0; nt < 8; ++nt) {
            const float s2 = v2t + p2v[nt];
            #pragma unroll
            for (int r = 0; r < 4; ++r) {
                const int al = ab + r;
                if (al < 100) {
                    float d2 = fmaxf(fmaf(-2.f, acc[h][nt][r], s2), 0.f) * 0.01f;
                    int vlog = voff + al;
                    if (d2 < minD[nt]) { minD[nt] = d2; minI[nt] = vlog; }
                    if (al == 0) sopen[voff ? 1 : 0][(ntb+nt)*16 + col] = d2;
                }
            }
        }
    }
}

// ---------------------------------------------------------------------------
// One block = one target t x all 1024 queries.  8 waves x 8 N-tiles each.
// ---------------------------------------------------------------------------
__global__ __launch_bounds__(512, 1) void matcher_mfma(
    const float* __restrict__ ws,      // p2 / v2 / pfrag / afrag
    const float* __restrict__ plog,    // [1024][2]
    const float* __restrict__ ptyp,    // [1024][4]
    const float* __restrict__ clog,    // [1024][2]
    const int*   __restrict__ labels,  // [256]
    const int*   __restrict__ iscl,    // [256]
    const float* __restrict__ clw,     // [256]
    float* __restrict__ out)           // [2][1024][256] flat fp32
{
    __shared__ float redD[4096];                      // [w][nt][rg*16+col]
    __shared__ int   redI[4096];
    __shared__ float sopen[2][1024];                  // d2[v=0], d2[v=100]

    const int t    = blockIdx.x;
    const int tid  = threadIdx.x;
    const int lane = tid & 63;
    const int w    = tid >> 6;          // wave 0..7 -> N-tiles w*8..w*8+7
    const int col  = lane & 15;
    const int rg   = lane >> 4;

    const float v2t = ws[1024 + t];
    const int ntb = w*8;
    float p2v[8];
    #pragma unroll
    for (int nt = 0; nt < 8; ++nt) p2v[nt] = ws[(ntb+nt)*16 + col];

    const f16x8* __restrict__ pfrag = (const f16x8*)(ws + WS_PF);
    const f16x8* __restrict__ afrag = (const f16x8*)(ws + WS_AF) + t*AFRAG_PER_T;

    float minD[8]; int minI[8];
    #pragma unroll
    for (int nt = 0; nt < 8; ++nt) { minD[nt] = 3.4028235e38f; minI[nt] = 0; }

    sweep< 0,4>(afrag, pfrag, ntb, lane, col, rg, v2t, p2v, minD, minI, sopen);
    sweep< 4,4>(afrag, pfrag, ntb, lane, col, rg, v2t, p2v, minD, minI, sopen);
    sweep< 8,4>(afrag, pfrag, ntb, lane, col, rg, v2t, p2v, minD, minI, sopen);
    sweep<12,2>(afrag, pfrag, ntb, lane, col, rg, v2t, p2v, minD, minI, sopen);

    #pragma unroll
    for (int nt = 0; nt < 8; ++nt) {
        redD[(w*8 + nt)*64 + lane] = minD[nt];
        redI[(w*8 + nt)*64 + lane] = minI[nt];
    }
    __syncthreads();

    // Epilogue: cross-row-group reduce (lexicographic (d,v) = first occurrence),
    // then cost-class terms; 2 queries per thread.
    for (int q = tid; q < Q_TOT; q += 512) {
        const int ww  = q >> 7;
        const int ntl = (q >> 4) & 7;
        const int cc  = q & 15;
        const int base = (ww*8 + ntl)*64 + cc;
        float bd = redD[base]; int bi = redI[base];
        #pragma unroll
        for (int g = 1; g < 4; ++g) {
            float d = redD[base + g*16]; int i = redI[base + g*16];
            if (d < bd || (d == bd && i < bi)) { bd = d; bi = i; }
        }
        int mapped = (bi <= NPTS-1) ? bi : (2*NPTS-1 - bi);
        float od   = fminf(sopen[0][q], sopen[1][q]);
        int   isc  = iscl[t];
        float geom = isc ? bd : od;
        int   ido  = isc ? mapped : 0;
        geom *= clw[t];

        float t0 = ptyp[q*4+0], t1 = ptyp[q*4+1];
        float t2 = ptyp[q*4+2], t3 = ptyp[q*4+3];
        float mx = fmaxf(fmaxf(t0,t1), fmaxf(t2,t3));
        float e0 = expf(t0-mx), e1 = expf(t1-mx), e2 = expf(t2-mx), e3 = expf(t3-mx);
        float rs = 1.0f/(e0+e1+e2+e3);
        int lab  = labels[t];
        float el = (lab == 0) ? e0 : (lab == 1) ? e1 : (lab == 2) ? e2 : e3;
        float cost = -logf(el*rs + EPSV);
        float v0 = plog[q*2+0], v1 = plog[q*2+1];
        cost += -logf(1.0f/(1.0f + expf(v1-v0)) + EPSV);
        float c0 = clog[q*2+0], c1 = clog[q*2+1];
        float pc = isc ? (1.0f/(1.0f + expf(c0-c1))) : (1.0f/(1.0f + expf(c1-c0)));
        cost += -logf(pc + EPSV);

        float C = geom + cost;
        out[q*T_TOT + t]               = C;
        out[Q_TOT*T_TOT + q*T_TOT + t] = (float)ido;
    }
}

extern "C" void kernel_launch(void* const* d_in, const int* in_sizes, int n_in,
                              void* d_out, int out_size, void* d_ws, size_t ws_size,
                              hipStream_t stream)
{
    const float* preds  = (const float*)d_in[0];  // pred_curve_points (1,1024,100,3)
    const float* plog   = (const float*)d_in[1];  // pred_curve_logits (1,1024,2)
    const float* ptyp   = (const float*)d_in[2];  // pred_curve_type   (1,1024,4)
    const float* clog   = (const float*)d_in[3];  // closed_curve_logits (1,1024,2)
    const float* tgt    = (const float*)d_in[4];  // tgt_curve_points  (256,100,3)
    const int*   labels = (const int*)d_in[5];    // tgt_labels (256)
    const int*   iscl   = (const int*)d_in[6];    // tgt_is_closed (256)
    const float* clw    = (const float*)d_in[7];  // curve_length_weighting (256)
    float* out = (float*)d_out;
    float* ws  = (float*)d_ws;    // needs ≈ 74.7 MB

    prep_all    <<<dim3(T_TOT), dim3(512), 0, stream>>>(preds, tgt, ws);
    matcher_mfma<<<dim3(T_TOT), dim3(512), 0, stream>>>(
        ws, plog, ptyp, clog, labels, iscl, clw, out);
}